// Round 3
// baseline (620.835 us; speedup 1.0000x reference)
//
#include <hip/hip_runtime.h>

#define NBINS   256
#define B       64
#define NPB     786432          // 3*512*512 elements per batch
#define NF4     (NPB / 4)       // 196608 float4 per batch
#define BPB     32              // blocks per batch
#define THREADS 256
#define GRID    (B * BPB)       // 2048 blocks = 8/CU on 256 CUs

#define SCOPE_AGENT __HIP_MEMORY_SCOPE_AGENT

// ws layout: ctrl [1024 u32]  (4 KB, zeroed by hipMemsetAsync each launch)
//              ctrl[0]      : global arrival ticket (entropy trigger)
//              ctrl[32 + b] : per-batch phase-1 arrival counter
//            pb   [GRID*2]  float  per-block {min,max} partials (16 KB)
//            hist [B*NBINS] u32    per-batch histograms (64 KB)
//
// Single fused kernel, NO cooperative launch (round 1 showed coop costs
// ~91 us/iter launch overhead + breaks graph capture). Synchronization:
//  - phase1->phase2: per-BATCH barrier (32 blocks) via device-scope counter.
//    Progress argument: a block waits only on its own aligned 32-block
//    group; groups are dispatched (approximately) in order and complete
//    independently, so no full-grid co-residency is required.
//  - phase2->entropy: last-arrival ticket; zero spinning.
// All cross-block data uses agent-scope atomics (per-XCD L2s are not
// coherent for plain loads/stores).

__global__ __launch_bounds__(THREADS, 8) void k_fused(const float4* __restrict__ x,
                                                      unsigned* __restrict__ ctrl,
                                                      float* __restrict__ pb,
                                                      unsigned* __restrict__ hist,
                                                      float* __restrict__ out) {
    const int batch = blockIdx.x / BPB;
    const int blk   = blockIdx.x % BPB;
    const float4* p = x + (size_t)batch * NF4;

    // ---- zero own batch's hist row (coherent stores; ordered by barrier) ----
    if (blk == 0)
        __hip_atomic_store(&hist[batch * NBINS + threadIdx.x], 0u,
                           __ATOMIC_RELAXED, SCOPE_AGENT);

    // ---------------- phase 1: per-block min/max ----------------
    float mn = 3.402823466e38f, mx = -3.402823466e38f;
    {
        int t = blk * THREADS + threadIdx.x;
        // NF4 / (BPB*THREADS) = 24 exact, no tail
        #pragma unroll 4
        for (int i = t; i < NF4; i += BPB * THREADS) {
            float4 v = p[i];
            mn = fminf(mn, fminf(fminf(v.x, v.y), fminf(v.z, v.w)));
            mx = fmaxf(mx, fmaxf(fmaxf(v.x, v.y), fmaxf(v.z, v.w)));
        }
        for (int o = 32; o > 0; o >>= 1) {
            mn = fminf(mn, __shfl_down(mn, o));
            mx = fmaxf(mx, __shfl_down(mx, o));
        }
        __shared__ float smn[4], smx[4];
        int wid = threadIdx.x >> 6;
        if ((threadIdx.x & 63) == 0) { smn[wid] = mn; smx[wid] = mx; }
        __syncthreads();
        if (threadIdx.x == 0) {
            mn = fminf(fminf(smn[0], smn[1]), fminf(smn[2], smn[3]));
            mx = fmaxf(fmaxf(smx[0], smx[1]), fmaxf(smx[2], smx[3]));
            __hip_atomic_store(&pb[2 * blockIdx.x],     mn, __ATOMIC_RELAXED, SCOPE_AGENT);
            __hip_atomic_store(&pb[2 * blockIdx.x + 1], mx, __ATOMIC_RELAXED, SCOPE_AGENT);
        }
    }

    // ---------------- per-batch barrier (32 blocks) ----------------
    if (threadIdx.x == 0) {
        __threadfence();                       // release pb stores + hist zeros
        atomicAdd(&ctrl[32 + batch], 1u);
        while (__hip_atomic_load(&ctrl[32 + batch], __ATOMIC_RELAXED, SCOPE_AGENT) < BPB)
            __builtin_amdgcn_s_sleep(2);
        __threadfence();                       // acquire
    }
    __syncthreads();

    // ---------------- phase 2: batch min/max + histogram ----------------
    __shared__ float rmn[BPB], rmx[BPB];
    if (threadIdx.x < BPB) {
        rmn[threadIdx.x] = __hip_atomic_load(&pb[2 * (batch * BPB + threadIdx.x)],
                                             __ATOMIC_RELAXED, SCOPE_AGENT);
        rmx[threadIdx.x] = __hip_atomic_load(&pb[2 * (batch * BPB + threadIdx.x) + 1],
                                             __ATOMIC_RELAXED, SCOPE_AGENT);
    }
    __syncthreads();
    float bmn = rmn[0], bmx = rmx[0];
    #pragma unroll
    for (int j = 1; j < BPB; ++j) {
        bmn = fminf(bmn, rmn[j]);
        bmx = fmaxf(bmx, rmx[j]);
    }
    // Match reference exactly: rng/lo selection, f32 divide then multiply,
    // truncating int cast, clip [0, 255].
    const float rng   = (bmx > bmn) ? (bmx - bmn) : 2.0f;
    const float lo    = (bmx > bmn) ? bmn : (bmn - 1.0f);
    const float scale = (float)NBINS / rng;

    // 4 per-wave replicas to keep LDS-atomic conflicts intra-wave only
    __shared__ unsigned lh[4][NBINS];
    for (int i = threadIdx.x; i < 4 * NBINS; i += THREADS)
        ((unsigned*)lh)[i] = 0u;
    __syncthreads();

    unsigned* h = lh[threadIdx.x >> 6];
    {
        int t = blk * THREADS + threadIdx.x;
        for (int i = t; i < NF4; i += BPB * THREADS) {
            float4 v = p[i];
            int i0 = (int)((v.x - lo) * scale);
            int i1 = (int)((v.y - lo) * scale);
            int i2 = (int)((v.z - lo) * scale);
            int i3 = (int)((v.w - lo) * scale);
            i0 = min(max(i0, 0), NBINS - 1);
            i1 = min(max(i1, 0), NBINS - 1);
            i2 = min(max(i2, 0), NBINS - 1);
            i3 = min(max(i3, 0), NBINS - 1);
            atomicAdd(&h[i0], 1u);
            atomicAdd(&h[i1], 1u);
            atomicAdd(&h[i2], 1u);
            atomicAdd(&h[i3], 1u);
        }
    }
    __syncthreads();

    unsigned* gh = hist + batch * NBINS;
    for (int i = threadIdx.x; i < NBINS; i += THREADS) {
        unsigned s = lh[0][i] + lh[1][i] + lh[2][i] + lh[3][i];
        if (s) atomicAdd(&gh[i], s);
    }
    __syncthreads();   // all this block's global atomics issued & drained

    // ---------------- last-block ticket -> entropy ----------------
    __shared__ int is_last;
    if (threadIdx.x == 0) {
        __threadfence();                       // release hist atomics
        unsigned t = atomicAdd(&ctrl[0], 1u);
        is_last = (t == GRID - 1);
        if (t == GRID - 1) __threadfence();    // acquire before reading hist
    }
    __syncthreads();
    if (!is_last) return;

    // Exact round-0 summation order (absmax == 0.0): per thread (= per bin)
    // sequential over b with ONE accumulator, then the 4-wave tree.
    const float invN = 1.0f / (float)NPB;
    float sum = 0.0f;
    #pragma unroll 8
    for (int b = 0; b < B; ++b) {
        unsigned c = __hip_atomic_load(&hist[b * NBINS + threadIdx.x],
                                       __ATOMIC_RELAXED, SCOPE_AGENT);
        if (c) {
            float pv = (float)c * invN;
            sum += pv * log2f(pv);
        }
    }
    for (int o = 32; o > 0; o >>= 1) sum += __shfl_down(sum, o);
    __shared__ float s4[4];
    int wid = threadIdx.x >> 6;
    if ((threadIdx.x & 63) == 0) s4[wid] = sum;
    __syncthreads();
    if (threadIdx.x == 0)
        out[0] = -(s4[0] + s4[1] + s4[2] + s4[3]) / (float)B;
}

extern "C" void kernel_launch(void* const* d_in, const int* in_sizes, int n_in,
                              void* d_out, int out_size, void* d_ws, size_t ws_size,
                              hipStream_t stream) {
    const float4* x = (const float4*)d_in[0];
    float* out      = (float*)d_out;
    unsigned* ctrl  = (unsigned*)d_ws;                                   // 4 KB
    float* pb       = (float*)((char*)d_ws + 4096);                      // 16 KB
    unsigned* hist  = (unsigned*)((char*)d_ws + 4096 + 2 * GRID * sizeof(float));

    // zero the sync counters (memset node is graph-capture legal)
    hipMemsetAsync(ctrl, 0, 4096, stream);
    hipLaunchKernelGGL(k_fused, dim3(GRID), dim3(THREADS), 0, stream,
                       x, ctrl, pb, hist, out);
}

// Round 4
// 331.387 us; speedup vs baseline: 1.8734x; 1.8734x over previous
//
#include <hip/hip_runtime.h>

#define NBINS   256
#define B       64
#define NPB     786432            // 3*512*512 elements per batch
#define NF4     (NPB / 4)         // 196608 float4 per batch
#define THREADS 256

#define BPB_MM   32               // minmax: blocks per batch
#define GRID_MM  (B * BPB_MM)     // 2048 blocks = 8/CU (HBM stream wants TLP)
#define STRIDE_MM (BPB_MM * THREADS)   // 8192 float4

#define BPB_H    16               // hist: blocks per batch
#define GRID_H   (B * BPB_H)      // 1024 blocks (halves LDS-zero + finale cost)
#define STRIDE_H (BPB_H * THREADS)     // 4096 float4

#define SCOPE_AGENT __HIP_MEMORY_SCOPE_AGENT

// ws layout: ctrl [1 u32]     last-block ticket (zeroed by k_minmax)
//            pb   [GRID_MM]   float2 per-block {min,max} partials
//            hist [B*NBINS]   u32 per-batch histograms (zeroed by k_minmax)
//
// Lesson from rounds 1/3: do NOT fuse the two data passes — per-block
// device-scope fences thrash the per-XCD L2s (streaming collapsed to
// ~0.5-0.6 TB/s). Kernel-boundary coherence is cheaper. Only the tiny
// entropy phase is fused (single ticket, ONE block pays an acquire fence).

// ---------------- kernel 1: per-block min/max (+ zero hist/ctrl) -----------
__global__ __launch_bounds__(THREADS) void k_minmax(const float4* __restrict__ x,
                                                    float2* __restrict__ pb,
                                                    unsigned* __restrict__ hist,
                                                    unsigned* __restrict__ ctrl) {
    // fold init in: first B blocks zero the per-batch histograms; block 0
    // zeroes the ticket. Plain stores — kernel boundary publishes them.
    if (blockIdx.x < B) hist[blockIdx.x * NBINS + threadIdx.x] = 0u;
    if (blockIdx.x == 0 && threadIdx.x == 0) ctrl[0] = 0u;

    const int batch = blockIdx.x / BPB_MM;
    const int blk   = blockIdx.x % BPB_MM;
    const float4* p = x + (size_t)batch * NF4;

    // Two independent accumulator pairs break the fminf/fmaxf dep chain.
    // Reordering min/max is exact for non-NaN data (input is uniform f32).
    float mnA = 3.402823466e38f, mxA = -3.402823466e38f;
    float mnB = 3.402823466e38f, mxB = -3.402823466e38f;
    const int t = blk * THREADS + threadIdx.x;
    // NF4 / STRIDE_MM = 24 exact, no tail
    #pragma unroll
    for (int j = 0; j < NF4 / STRIDE_MM; j += 2) {
        float4 a = p[t + j * STRIDE_MM];
        float4 b = p[t + (j + 1) * STRIDE_MM];
        mnA = fminf(mnA, fminf(fminf(a.x, a.y), fminf(a.z, a.w)));
        mxA = fmaxf(mxA, fmaxf(fmaxf(a.x, a.y), fmaxf(a.z, a.w)));
        mnB = fminf(mnB, fminf(fminf(b.x, b.y), fminf(b.z, b.w)));
        mxB = fmaxf(mxB, fmaxf(fmaxf(b.x, b.y), fmaxf(b.z, b.w)));
    }
    float mn = fminf(mnA, mnB), mx = fmaxf(mxA, mxB);

    // wave64 reduce
    for (int o = 32; o > 0; o >>= 1) {
        mn = fminf(mn, __shfl_down(mn, o));
        mx = fmaxf(mx, __shfl_down(mx, o));
    }
    __shared__ float smn[4], smx[4];
    int wid = threadIdx.x >> 6;
    if ((threadIdx.x & 63) == 0) { smn[wid] = mn; smx[wid] = mx; }
    __syncthreads();
    if (threadIdx.x == 0) {
        mn = fminf(fminf(smn[0], smn[1]), fminf(smn[2], smn[3]));
        mx = fmaxf(fmaxf(smx[0], smx[1]), fmaxf(smx[2], smx[3]));
        pb[blockIdx.x] = make_float2(mn, mx);   // plain store, no atomics
    }
}

// ---------------- kernel 2: histogram + last-block entropy -----------------
__global__ __launch_bounds__(THREADS) void k_hist(const float4* __restrict__ x,
                                                  const float2* __restrict__ pb,
                                                  unsigned* __restrict__ hist,
                                                  unsigned* __restrict__ ctrl,
                                                  float* __restrict__ out) {
    const int batch = blockIdx.x / BPB_H;
    const int blk   = blockIdx.x % BPB_H;

    // reduce this batch's BPB_MM per-block partials (uniform scalar loads)
    float mn = 3.402823466e38f, mx = -3.402823466e38f;
    #pragma unroll
    for (int j = 0; j < BPB_MM; ++j) {
        float2 v = pb[batch * BPB_MM + j];
        mn = fminf(mn, v.x);
        mx = fmaxf(mx, v.y);
    }
    // Match reference exactly: rng/lo selection, f32 divide then multiply,
    // truncating int cast, clip [0, 255].
    const float rng   = (mx > mn) ? (mx - mn) : 2.0f;
    const float lo    = (mx > mn) ? mn : (mn - 1.0f);
    const float scale = (float)NBINS / rng;

    // 4 per-wave replicas keep LDS-atomic conflicts intra-wave only
    __shared__ unsigned lh[4][NBINS];
    for (int i = threadIdx.x; i < 4 * NBINS; i += THREADS)
        ((unsigned*)lh)[i] = 0u;
    __syncthreads();

    unsigned* h = lh[threadIdx.x >> 6];
    const float4* p = x + (size_t)batch * NF4;
    const int t = blk * THREADS + threadIdx.x;
    // NF4 / STRIDE_H = 48 exact; unroll for load ILP over the DS-atomic waits
    #pragma unroll 4
    for (int i = t; i < NF4; i += STRIDE_H) {
        float4 v = p[i];
        int i0 = (int)((v.x - lo) * scale);
        int i1 = (int)((v.y - lo) * scale);
        int i2 = (int)((v.z - lo) * scale);
        int i3 = (int)((v.w - lo) * scale);
        i0 = min(max(i0, 0), NBINS - 1);
        i1 = min(max(i1, 0), NBINS - 1);
        i2 = min(max(i2, 0), NBINS - 1);
        i3 = min(max(i3, 0), NBINS - 1);
        atomicAdd(&h[i0], 1u);
        atomicAdd(&h[i1], 1u);
        atomicAdd(&h[i2], 1u);
        atomicAdd(&h[i3], 1u);
    }
    __syncthreads();

    unsigned* gh = hist + batch * NBINS;
    for (int i = threadIdx.x; i < NBINS; i += THREADS) {
        unsigned s = lh[0][i] + lh[1][i] + lh[2][i] + lh[3][i];
        if (s) atomicAdd(&gh[i], s);
    }
    // __syncthreads drains vmcnt -> this block's global atomics are performed
    // at the coherent point before thread 0 issues the ticket.
    __syncthreads();

    __shared__ unsigned last;
    if (threadIdx.x == 0) {
        unsigned tk = __hip_atomic_fetch_add(&ctrl[0], 1u,
                                             __ATOMIC_ACQ_REL, SCOPE_AGENT);
        last = (tk == GRID_H - 1) ? 1u : 0u;
    }
    __syncthreads();
    if (!last) return;

    // ---------------- entropy (exact round-0 summation order) --------------
    __threadfence();   // acquire: ONE block invalidates before reading hist
    const float invN = 1.0f / (float)NPB;
    float sum = 0.0f;
    #pragma unroll 8
    for (int b = 0; b < B; ++b) {
        unsigned c = __hip_atomic_load(&hist[b * NBINS + threadIdx.x],
                                       __ATOMIC_RELAXED, SCOPE_AGENT);
        if (c) {
            float pv = (float)c * invN;
            sum += pv * log2f(pv);
        }
    }
    for (int o = 32; o > 0; o >>= 1) sum += __shfl_down(sum, o);
    __shared__ float s4[4];
    int wid = threadIdx.x >> 6;
    if ((threadIdx.x & 63) == 0) s4[wid] = sum;
    __syncthreads();
    if (threadIdx.x == 0)
        out[0] = -(s4[0] + s4[1] + s4[2] + s4[3]) / (float)B;
}

extern "C" void kernel_launch(void* const* d_in, const int* in_sizes, int n_in,
                              void* d_out, int out_size, void* d_ws, size_t ws_size,
                              hipStream_t stream) {
    const float4* x = (const float4*)d_in[0];
    float* out      = (float*)d_out;
    unsigned* ctrl  = (unsigned*)d_ws;                                   // 4 B (pad to 256)
    float2* pb      = (float2*)((char*)d_ws + 256);                      // 16 KB
    unsigned* hist  = (unsigned*)((char*)d_ws + 256 + GRID_MM * sizeof(float2));

    hipLaunchKernelGGL(k_minmax, dim3(GRID_MM), dim3(THREADS), 0, stream,
                       x, pb, hist, ctrl);
    hipLaunchKernelGGL(k_hist, dim3(GRID_H), dim3(THREADS), 0, stream,
                       x, pb, hist, ctrl, out);
}

// Round 5
// 300.026 us; speedup vs baseline: 2.0693x; 1.1045x over previous
//
#include <hip/hip_runtime.h>

#define NBINS   256
#define B       64
#define NPB     786432            // 3*512*512 elements per batch
#define NF4     (NPB / 4)         // 196608 float4 per batch
#define THREADS 256
#define BPB     16                // blocks per batch (round-0 proven shape)
#define GRID    (B * BPB)         // 1024 blocks
#define STRIDE  (BPB * THREADS)   // 4096 float4; NF4/STRIDE = 48 exact

// ws layout: pb   [GRID]    float2  per-block {min,max} partials (8 KB)
//            hist [B*NBINS] u32     per-batch histograms (64 KB)
//
// Structure lesson (rounds 1/3/4): every intra-kernel cross-block sync
// (coop grid.sync, per-batch barrier+fences, last-block acq_rel ticket)
// regressed 25-230 us — per-block agent-scope ordering ops thrash the
// per-XCD L2s. Plain kernel boundaries win. Keep 3 split kernels.

// ---------------- kernel 1: per-block min/max (+ zero hist) ----------------
__global__ __launch_bounds__(THREADS) void k_minmax(const float4* __restrict__ x,
                                                    float2* __restrict__ pb,
                                                    unsigned* __restrict__ hist) {
    // Fold init in: first B blocks zero the per-batch histograms (hist is
    // only written by k_hist, after the kernel boundary -> race-free).
    // pb needs no init: plain per-block stores, no atomics.
    if (blockIdx.x < B) hist[blockIdx.x * NBINS + threadIdx.x] = 0u;

    const int batch = blockIdx.x / BPB;
    const int blk   = blockIdx.x % BPB;
    const float4* p = x + (size_t)batch * NF4;

    float mn = 3.402823466e38f, mx = -3.402823466e38f;
    int t = blk * THREADS + threadIdx.x;
    #pragma unroll 4
    for (int i = t; i < NF4; i += STRIDE) {
        float4 v = p[i];
        mn = fminf(mn, fminf(fminf(v.x, v.y), fminf(v.z, v.w)));
        mx = fmaxf(mx, fmaxf(fmaxf(v.x, v.y), fmaxf(v.z, v.w)));
    }
    // wave64 reduce
    for (int o = 32; o > 0; o >>= 1) {
        mn = fminf(mn, __shfl_down(mn, o));
        mx = fmaxf(mx, __shfl_down(mx, o));
    }
    __shared__ float smn[4], smx[4];
    int wid = threadIdx.x >> 6;
    if ((threadIdx.x & 63) == 0) { smn[wid] = mn; smx[wid] = mx; }
    __syncthreads();
    if (threadIdx.x == 0) {
        mn = fminf(fminf(smn[0], smn[1]), fminf(smn[2], smn[3]));
        mx = fmaxf(fmaxf(smx[0], smx[1]), fmaxf(smx[2], smx[3]));
        pb[blockIdx.x] = make_float2(mn, mx);   // plain store, no atomics
    }
}

// ---------------- kernel 2: histogram (8 LDS replicas) ---------------------
__global__ __launch_bounds__(THREADS) void k_hist(const float4* __restrict__ x,
                                                  const float2* __restrict__ pb,
                                                  unsigned* __restrict__ hist) {
    const int batch = blockIdx.x / BPB;
    const int blk   = blockIdx.x % BPB;

    // reduce this batch's BPB per-block partials (uniform scalar loads)
    float mn = 3.402823466e38f, mx = -3.402823466e38f;
    #pragma unroll
    for (int j = 0; j < BPB; ++j) {
        float2 v = pb[batch * BPB + j];
        mn = fminf(mn, v.x);
        mx = fmaxf(mx, v.y);
    }
    // Match reference exactly: rng/lo selection, f32 divide then multiply,
    // truncating int cast, clip [0, 255].
    const float rng   = (mx > mn) ? (mx - mn) : 2.0f;
    const float lo    = (mx > mn) ? mn : (mn - 1.0f);
    const float scale = (float)NBINS / rng;

    // 8 replicas: one per 32-lane half-wave. Same-table atomic pressure
    // drops from 64 lanes to 32 (expected bank-conflict cycles ~halved
    // vs the 4-replica round-0 version).
    __shared__ unsigned lh[8][NBINS];
    for (int i = threadIdx.x; i < 8 * NBINS; i += THREADS)
        ((unsigned*)lh)[i] = 0u;
    __syncthreads();

    unsigned* h = lh[threadIdx.x >> 5];
    const float4* p = x + (size_t)batch * NF4;
    int t = blk * THREADS + threadIdx.x;
    #pragma unroll 4
    for (int i = t; i < NF4; i += STRIDE) {
        float4 v = p[i];
        int i0 = (int)((v.x - lo) * scale);
        int i1 = (int)((v.y - lo) * scale);
        int i2 = (int)((v.z - lo) * scale);
        int i3 = (int)((v.w - lo) * scale);
        i0 = min(max(i0, 0), NBINS - 1);
        i1 = min(max(i1, 0), NBINS - 1);
        i2 = min(max(i2, 0), NBINS - 1);
        i3 = min(max(i3, 0), NBINS - 1);
        atomicAdd(&h[i0], 1u);
        atomicAdd(&h[i1], 1u);
        atomicAdd(&h[i2], 1u);
        atomicAdd(&h[i3], 1u);
    }
    __syncthreads();

    unsigned* gh = hist + batch * NBINS;
    for (int i = threadIdx.x; i < NBINS; i += THREADS) {
        unsigned s = (lh[0][i] + lh[1][i]) + (lh[2][i] + lh[3][i])
                   + (lh[4][i] + lh[5][i]) + (lh[6][i] + lh[7][i]);
        if (s) atomicAdd(&gh[i], s);
    }
}

// ---------------- kernel 3: entropy (exact round-0 order) ------------------
__global__ __launch_bounds__(THREADS) void k_entropy(const unsigned* __restrict__ hist,
                                                     float* __restrict__ out) {
    // Every element lands in exactly one bin (clip), so per-batch sum == NPB.
    // Single accumulator, sequential over b: summation order bitwise-identical
    // to the absmax==0.0 baseline; unroll only adds load ILP.
    const float invN = 1.0f / (float)NPB;
    float sum = 0.0f;
    #pragma unroll 8
    for (int b = 0; b < B; ++b) {
        unsigned c = hist[b * NBINS + threadIdx.x];
        if (c) {
            float pv = (float)c * invN;
            sum += pv * log2f(pv);
        }
    }
    for (int o = 32; o > 0; o >>= 1) sum += __shfl_down(sum, o);
    __shared__ float s[4];
    int wid = threadIdx.x >> 6;
    if ((threadIdx.x & 63) == 0) s[wid] = sum;
    __syncthreads();
    if (threadIdx.x == 0)
        out[0] = -(s[0] + s[1] + s[2] + s[3]) / (float)B;
}

extern "C" void kernel_launch(void* const* d_in, const int* in_sizes, int n_in,
                              void* d_out, int out_size, void* d_ws, size_t ws_size,
                              hipStream_t stream) {
    const float4* x = (const float4*)d_in[0];
    float* out      = (float*)d_out;
    float2* pb      = (float2*)d_ws;                                    // 8 KB
    unsigned* hist  = (unsigned*)((char*)d_ws + GRID * sizeof(float2)); // 64 KB

    hipLaunchKernelGGL(k_minmax, dim3(GRID), dim3(THREADS), 0, stream,
                       x, pb, hist);
    hipLaunchKernelGGL(k_hist, dim3(GRID), dim3(THREADS), 0, stream,
                       x, pb, hist);
    hipLaunchKernelGGL(k_entropy, dim3(1), dim3(THREADS), 0, stream,
                       hist, out);
}